// Round 13
// baseline (152.474 us; speedup 1.0000x reference)
//
#include <hip/hip_runtime.h>
#include <hip/hip_bf16.h>

#define NB 4
#define CDIM 128
#define NPIX 1600
#define WIMG 40
#define HCH 256
#define NHEADS 8
#define KDQ 8
#define HDV 16
#define EPSV 1e-3f
#define SCALEV 0.35355339059327373f

typedef unsigned short u16;
typedef float f32x4 __attribute__((ext_vector_type(4)));
typedef __bf16 bf16x8 __attribute__((ext_vector_type(8)));

union U16B { uint4 u; bf16x8 v; };

__device__ __forceinline__ u16 f2bf(float f) {   // RNE float->bf16 bits
  unsigned u = __float_as_uint(f);
  return (u16)((u + 0x7FFFu + ((u >> 16) & 1u)) >> 16);
}
__device__ __forceinline__ float bf2f(u16 b) {
  return __uint_as_float(((unsigned)b) << 16);
}
__device__ __forceinline__ unsigned cvt_pk_bf16(float lo, float hi) {
  unsigned r;
  asm("v_cvt_pk_bf16_f32 %0, %1, %2" : "=v"(r) : "v"(lo), "v"(hi));
  return r;
}

// ---------------- K1: qkv = BN(conv1x1(x)), split-K over ci ----------------
// 512 threads: half 0/1 each accumulate 64 ci, LDS-reduce, half 0 stores.
// Emits q/k as hi+lo bf16 split rows ([n][16]), v^T bf16 ([d][n]), fp32 v.
__global__ __launch_bounds__(512) void k_qkv(
    const float* __restrict__ x, const float* __restrict__ w,
    const float* __restrict__ gg, const float* __restrict__ bb,
    const float* __restrict__ mm, const float* __restrict__ vv,
    float* __restrict__ vf32, u16* __restrict__ qbf,
    u16* __restrict__ kbf, u16* __restrict__ vtbf)
{
  const int pblk = blockIdx.x % 7;
  const int ct   = (blockIdx.x / 7) % (HCH / 8);
  const int b    = blockIdx.x / (7 * (HCH / 8));
  const int tid  = threadIdx.x;
  const int half = tid >> 8;
  const int t    = tid & 255;

  __shared__ float wl[8][CDIM];
  __shared__ float red[256][8];
  for (int i = tid; i < 8 * CDIM; i += 512)
    wl[i >> 7][i & 127] = w[(ct * 8 + (i >> 7)) * CDIM + (i & 127)];
  __syncthreads();

  const int praw = pblk * 256 + t;
  const int p    = praw < NPIX ? praw : NPIX - 1;   // clamp (no early return)

  const float* xb = x + (size_t)b * CDIM * NPIX + p;
  float acc[8] = {0.f, 0.f, 0.f, 0.f, 0.f, 0.f, 0.f, 0.f};
  const int c0 = half * 64;
#pragma unroll 8
  for (int ci = c0; ci < c0 + 64; ++ci) {
    const float xv = xb[(size_t)ci * NPIX];
#pragma unroll
    for (int j = 0; j < 8; ++j) acc[j] += wl[j][ci] * xv;
  }

  if (half == 1) {
#pragma unroll
    for (int j = 0; j < 8; ++j) red[t][j] = acc[j];
  }
  __syncthreads();
  if (half == 1 || praw >= NPIX) return;
#pragma unroll
  for (int j = 0; j < 8; ++j) acc[j] += red[t][j];

  const int grp = ct & 3;   // 0=q(kd0-7) 1=k(kd0-7) 2=v(d0-7) 3=v(d8-15)
  const int h   = ct >> 2;
  float o[8];
#pragma unroll
  for (int j = 0; j < 8; ++j) {
    const int c = ct * 8 + j;
    const float sc = gg[c] * rsqrtf(vv[c] + EPSV);
    const float bi = bb[c] - mm[c] * sc;
    o[j] = acc[j] * sc + bi;
    if (grp == 0) o[j] *= SCALEV;
  }

  if (grp <= 1) {
    u16 hb[8], lb[8];
#pragma unroll
    for (int j = 0; j < 8; ++j) {
      hb[j] = f2bf(o[j]);
      lb[j] = f2bf(o[j] - bf2f(hb[j]));
    }
    uint4 H, L;
    H.x = hb[0] | ((unsigned)hb[1] << 16);
    H.y = hb[2] | ((unsigned)hb[3] << 16);
    H.z = hb[4] | ((unsigned)hb[5] << 16);
    H.w = hb[6] | ((unsigned)hb[7] << 16);
    L.x = lb[0] | ((unsigned)lb[1] << 16);
    L.y = lb[2] | ((unsigned)lb[3] << 16);
    L.z = lb[4] | ((unsigned)lb[5] << 16);
    L.w = lb[6] | ((unsigned)lb[7] << 16);
    u16* dst = (grp == 0) ? qbf : kbf;
    const size_t base = ((size_t)(b * NHEADS + h) * NPIX + p) * 16;
    *(uint4*)&dst[base]     = H;
    *(uint4*)&dst[base + 8] = L;
  } else {
    const int d0 = (grp == 2) ? 0 : 8;
#pragma unroll
    for (int j = 0; j < 8; ++j) {
      vtbf[((size_t)(b * NHEADS + h) * HDV + d0 + j) * NPIX + p] = f2bf(o[j]);
      vf32[((size_t)b * CDIM + h * HDV + d0 + j) * NPIX + p] = o[j];
    }
  }
}

// ---------------- K2: MFMA attention, NO K/V staging (L2-resident) ----------------
// 512 thr = 8 waves: wave (qw = wid&3, kh = wid>>2) handles query sub-tile qw
// (16 queries) and key-half kh (800 keys, 25 x 32-key steps) read DIRECTLY
// from global (kbf+vtbf = 3.3 MB, L2-fits; staging was pure overhead).
// Barrier-free main loop; one __syncthreads for the kh-partial combine.
// kh=0 waves run the fused epilogue: atb = attn/lsum + BN(dwconv3x3(v)).
__global__ __launch_bounds__(512) void k_attn(
    const u16* __restrict__ qbf, const u16* __restrict__ kbf,
    const u16* __restrict__ vtbf, const float* __restrict__ vf32,
    const float* __restrict__ pw, const float* __restrict__ pg,
    const float* __restrict__ pbb, const float* __restrict__ pm,
    const float* __restrict__ pv, float* __restrict__ atb)
{
  const int bh   = blockIdx.x & 31;
  const int qblk = blockIdx.x >> 5;          // 0..24
  const int b = bh >> 3, h = bh & 7;
  const int tid = threadIdx.x;
  const int lane = tid & 63, wid = tid >> 6;
  const int qw = wid & 3, kh = wid >> 2;
  const int qloc = lane & 15, g = lane >> 4;

  __shared__ float red[256][5];   // kh=1 partials: c3[0..3], lsum (stride 5: conflict-free)

  const int qglob = qblk * 64 + qw * 16 + qloc;
  U16B qf;
  qf.u = *(const uint4*)&qbf[((size_t)bh * NPIX + qglob) * 16 + (g & 1) * 8];

  f32x4 c3 = {0.f, 0.f, 0.f, 0.f};
  float lsum = 0.f;
  const int idx0 = (((g & 1) << 5) | qloc) << 2;  // bpermute byte index
  const int idx1 = idx0 + 64;                     // +16 lanes
  const bool selA = (g < 2);
  const f32x4 zf = {0.f, 0.f, 0.f, 0.f};
  const int ksel = (g >> 1) * 8;                  // K-frag hi/lo select

  const u16* kbase = kbf + (size_t)bh * NPIX * 16;
  const u16* vbase = vtbf + ((size_t)bh * HDV + qloc) * NPIX;

  for (int s = 0; s < 25; ++s) {
    const int key0 = kh * 800 + s * 32;
    // K fragments (A-operand) straight from L2: rows key0+qloc / +16+qloc,
    // hi half for g<2, lo half for g>=2 (hi/lo split-precision QK^T).
    U16B kfA, kfB, vf4;
    kfA.u = *(const uint4*)&kbase[(size_t)(key0 + qloc) * 16 + ksel];
    kfB.u = *(const uint4*)&kbase[(size_t)(key0 + 16 + qloc) * 16 + ksel];
    // V^T fragment (A-operand): Vt[d=qloc][keys key0+8g..+8g+7]
    vf4.u = *(const uint4*)&vbase[key0 + g * 8];

    f32x4 cA = __builtin_amdgcn_mfma_f32_16x16x32_bf16(kfA.v, qf.v, zf, 0, 0, 0);
    f32x4 cB = __builtin_amdgcn_mfma_f32_16x16x32_bf16(kfB.v, qf.v, zf, 0, 0, 0);

    const unsigned pkA0 = cvt_pk_bf16(__expf(cA[0]), __expf(cA[1]));
    const unsigned pkA1 = cvt_pk_bf16(__expf(cA[2]), __expf(cA[3]));
    const unsigned pkB0 = cvt_pk_bf16(__expf(cB[0]), __expf(cB[1]));
    const unsigned pkB1 = cvt_pk_bf16(__expf(cB[2]), __expf(cB[3]));

    // Rearrange P (C-layout) -> B-frag layout: lane needs keys 8g..8g+7
    // of this 32-key step for its query qloc.
    const int a0 = __builtin_amdgcn_ds_bpermute(idx0, (int)pkA0);
    const int b0 = __builtin_amdgcn_ds_bpermute(idx0, (int)pkB0);
    const int a1 = __builtin_amdgcn_ds_bpermute(idx0, (int)pkA1);
    const int b1 = __builtin_amdgcn_ds_bpermute(idx0, (int)pkB1);
    const int a2 = __builtin_amdgcn_ds_bpermute(idx1, (int)pkA0);
    const int b2 = __builtin_amdgcn_ds_bpermute(idx1, (int)pkB0);
    const int a3 = __builtin_amdgcn_ds_bpermute(idx1, (int)pkA1);
    const int b3 = __builtin_amdgcn_ds_bpermute(idx1, (int)pkB1);
    U16B pf;
    pf.u.x = (unsigned)(selA ? a0 : b0);
    pf.u.y = (unsigned)(selA ? a1 : b1);
    pf.u.z = (unsigned)(selA ? a2 : b2);
    pf.u.w = (unsigned)(selA ? a3 : b3);

    // lsum from the QUANTIZED P (num/denom use identical weights).
    lsum += __uint_as_float(pf.u.x << 16) + __uint_as_float(pf.u.x & 0xFFFF0000u)
          + __uint_as_float(pf.u.y << 16) + __uint_as_float(pf.u.y & 0xFFFF0000u)
          + __uint_as_float(pf.u.z << 16) + __uint_as_float(pf.u.z & 0xFFFF0000u)
          + __uint_as_float(pf.u.w << 16) + __uint_as_float(pf.u.w & 0xFFFF0000u);

    c3 = __builtin_amdgcn_mfma_f32_16x16x32_bf16(vf4.v, pf.v, c3, 0, 0, 0);
  }

  // combine key halves across wave pairs (kh=1 -> kh=0); one barrier total
  if (kh == 1) {
    const int rr = qw * 64 + lane;
    red[rr][0] = c3[0]; red[rr][1] = c3[1];
    red[rr][2] = c3[2]; red[rr][3] = c3[3];
    red[rr][4] = lsum;
  }
  __syncthreads();
  if (kh == 1) return;
  {
    const int rr = qw * 64 + lane;
    c3[0] += red[rr][0]; c3[1] += red[rr][1];
    c3[2] += red[rr][2]; c3[3] += red[rr][3];
    lsum  += red[rr][4];
  }

  lsum += __shfl_xor(lsum, 16);
  lsum += __shfl_xor(lsum, 32);
  const float rl = 1.f / lsum;

  // Epilogue: atb[d][p] = c3[r]*rl + BN(dwconv3x3(v))[c=h*16+d][p]
  const int p  = qblk * 64 + qw * 16 + qloc;
  const int yy = p / WIMG, xx = p % WIMG;
  const float* vb = vf32 + ((size_t)b * CDIM + h * HDV) * NPIX;
  float* ob = atb + ((size_t)b * CDIM + h * HDV) * NPIX + p;
#pragma unroll
  for (int r = 0; r < 4; ++r) {
    const int d = g * 4 + r;
    const int c = h * HDV + d;
    float acc = 0.f;
#pragma unroll
    for (int dy = -1; dy <= 1; ++dy)
#pragma unroll
      for (int dx = -1; dx <= 1; ++dx) {
        const int y2 = yy + dy, x2 = xx + dx;
        if ((unsigned)y2 < (unsigned)WIMG && (unsigned)x2 < (unsigned)WIMG)
          acc += pw[c * 9 + (dy + 1) * 3 + (dx + 1)] * vb[(size_t)d * NPIX + y2 * WIMG + x2];
      }
    const float sc = pg[c] * rsqrtf(pv[c] + EPSV);
    const float bi = pbb[c] - pm[c] * sc;
    ob[(size_t)d * NPIX] = c3[r] * rl + acc * sc + bi;
  }
}

// ---------------- K3: y = BN(conv1x1(atb)) -> f32 out ----------------
// 2 output channels per block: 1792 blocks -> 28 waves/CU; unroll 16 for ILP.
__global__ __launch_bounds__(256) void k_proj(
    const float* __restrict__ atb, const float* __restrict__ w,
    const float* __restrict__ gg, const float* __restrict__ bb,
    const float* __restrict__ mm, const float* __restrict__ vv,
    float* __restrict__ out)
{
  const int pblk = blockIdx.x % 7;
  const int ct   = (blockIdx.x / 7) % (CDIM / 2);
  const int b    = blockIdx.x / (7 * (CDIM / 2));
  const int tid  = threadIdx.x;

  __shared__ float wl[2][CDIM];
  wl[tid >> 7][tid & 127] = w[(ct * 2 + (tid >> 7)) * CDIM + (tid & 127)];
  __syncthreads();

  const int p = pblk * 256 + tid;
  if (p >= NPIX) return;

  const float* ab = atb + (size_t)b * CDIM * NPIX + p;
  float a0 = 0.f, a1 = 0.f;
#pragma unroll 16
  for (int ci = 0; ci < CDIM; ++ci) {
    const float xv = ab[(size_t)ci * NPIX];
    a0 += wl[0][ci] * xv;
    a1 += wl[1][ci] * xv;
  }
#pragma unroll
  for (int j = 0; j < 2; ++j) {
    const int c = ct * 2 + j;
    const float sc = gg[c] * rsqrtf(vv[c] + EPSV);
    const float bi = bb[c] - mm[c] * sc;
    out[((size_t)b * CDIM + c) * NPIX + p] = (j ? a1 : a0) * sc + bi;
  }
}

extern "C" void kernel_launch(void* const* d_in, const int* in_sizes, int n_in,
                              void* d_out, int out_size, void* d_ws, size_t ws_size,
                              hipStream_t stream)
{
  const float* x      = (const float*)d_in[0];
  const float* qkv_w  = (const float*)d_in[1];
  const float* qkv_g  = (const float*)d_in[2];
  const float* qkv_b  = (const float*)d_in[3];
  const float* qkv_m  = (const float*)d_in[4];
  const float* qkv_v  = (const float*)d_in[5];
  const float* pe_w   = (const float*)d_in[6];
  const float* pe_g   = (const float*)d_in[7];
  const float* pe_b   = (const float*)d_in[8];
  const float* pe_m   = (const float*)d_in[9];
  const float* pe_v   = (const float*)d_in[10];
  const float* proj_w = (const float*)d_in[11];
  const float* proj_g = (const float*)d_in[12];
  const float* proj_b = (const float*)d_in[13];
  const float* proj_m = (const float*)d_in[14];
  const float* proj_v = (const float*)d_in[15];

  float* ws   = (float*)d_ws;
  float* vf32 = ws;                                  // 819,200 f
  float* atb  = vf32 + (size_t)NB * CDIM * NPIX;     // 819,200 f
  u16*   qbf  = (u16*)(atb + (size_t)NB * CDIM * NPIX);        // 819,200 u16 (hi+lo)
  u16*   kbf  = qbf + (size_t)NB * NHEADS * NPIX * 16;         // 819,200 u16 (hi+lo)
  u16*   vtbf = kbf + (size_t)NB * NHEADS * NPIX * 16;         // 819,200 u16

  k_qkv<<<dim3(NB * (HCH / 8) * 7), 512, 0, stream>>>(
      x, qkv_w, qkv_g, qkv_b, qkv_m, qkv_v, vf32, qbf, kbf, vtbf);
  k_attn<<<dim3(NB * NHEADS * 25), 512, 0, stream>>>(
      qbf, kbf, vtbf, vf32, pe_w, pe_g, pe_b, pe_m, pe_v, atb);
  k_proj<<<dim3(NB * (CDIM / 2) * 7), 256, 0, stream>>>(
      atb, proj_w, proj_g, proj_b, proj_m, proj_v, (float*)d_out);
}

// Round 15
// 149.495 us; speedup vs baseline: 1.0199x; 1.0199x over previous
//
#include <hip/hip_runtime.h>
#include <hip/hip_bf16.h>

#define NB 4
#define CDIM 128
#define NPIX 1600
#define WIMG 40
#define HCH 256
#define NHEADS 8
#define KDQ 8
#define HDV 16
#define EPSV 1e-3f
#define SCALEV 0.35355339059327373f

typedef unsigned short u16;
typedef float f32x4 __attribute__((ext_vector_type(4)));
typedef __bf16 bf16x8 __attribute__((ext_vector_type(8)));

union U16B { uint4 u; bf16x8 v; };

__device__ __forceinline__ u16 f2bf(float f) {   // RNE float->bf16 bits
  unsigned u = __float_as_uint(f);
  return (u16)((u + 0x7FFFu + ((u >> 16) & 1u)) >> 16);
}
__device__ __forceinline__ float bf2f(u16 b) {
  return __uint_as_float(((unsigned)b) << 16);
}
__device__ __forceinline__ unsigned cvt_pk_bf16(float lo, float hi) {
  unsigned r;
  asm("v_cvt_pk_bf16_f32 %0, %1, %2" : "=v"(r) : "v"(lo), "v"(hi));
  return r;
}

// ---------------- K1: qkv = BN(conv1x1(x)), split-K over ci ----------------
// Grid order: ct fastest -> the 32 blocks sharing one x-slice dispatch
// together (per-XCD L2 reuse). 512 thr: halves accumulate 64 ci, LDS-reduce.
__global__ __launch_bounds__(512) void k_qkv(
    const float* __restrict__ x, const float* __restrict__ w,
    const float* __restrict__ gg, const float* __restrict__ bb,
    const float* __restrict__ mm, const float* __restrict__ vv,
    float* __restrict__ vf32, u16* __restrict__ qbf,
    u16* __restrict__ kbf, u16* __restrict__ vtbf)
{
  const int ct   = blockIdx.x % (HCH / 8);
  const int pblk = (blockIdx.x / (HCH / 8)) % 7;
  const int b    = blockIdx.x / (7 * (HCH / 8));
  const int tid  = threadIdx.x;
  const int half = tid >> 8;
  const int t    = tid & 255;

  __shared__ float wl[8][CDIM];
  __shared__ float red[256][8];
  for (int i = tid; i < 8 * CDIM; i += 512)
    wl[i >> 7][i & 127] = w[(ct * 8 + (i >> 7)) * CDIM + (i & 127)];
  __syncthreads();

  const int praw = pblk * 256 + t;
  const int p    = praw < NPIX ? praw : NPIX - 1;   // clamp (no early return)

  const float* xb = x + (size_t)b * CDIM * NPIX + p;
  float acc[8] = {0.f, 0.f, 0.f, 0.f, 0.f, 0.f, 0.f, 0.f};
  const int c0 = half * 64;
#pragma unroll 8
  for (int ci = c0; ci < c0 + 64; ++ci) {
    const float xv = xb[(size_t)ci * NPIX];
#pragma unroll
    for (int j = 0; j < 8; ++j) acc[j] += wl[j][ci] * xv;
  }

  if (half == 1) {
#pragma unroll
    for (int j = 0; j < 8; ++j) red[t][j] = acc[j];
  }
  __syncthreads();
  if (half == 1 || praw >= NPIX) return;
#pragma unroll
  for (int j = 0; j < 8; ++j) acc[j] += red[t][j];

  const int grp = ct & 3;   // 0=q(kd0-7) 1=k(kd0-7) 2=v(d0-7) 3=v(d8-15)
  const int h   = ct >> 2;
  float o[8];
#pragma unroll
  for (int j = 0; j < 8; ++j) {
    const int c = ct * 8 + j;
    const float sc = gg[c] * rsqrtf(vv[c] + EPSV);
    const float bi = bb[c] - mm[c] * sc;
    o[j] = acc[j] * sc + bi;
    if (grp == 0) o[j] *= SCALEV;
  }

  if (grp <= 1) {
    u16 hb[8], lb[8];
#pragma unroll
    for (int j = 0; j < 8; ++j) {
      hb[j] = f2bf(o[j]);
      lb[j] = f2bf(o[j] - bf2f(hb[j]));
    }
    uint4 H, L;
    H.x = hb[0] | ((unsigned)hb[1] << 16);
    H.y = hb[2] | ((unsigned)hb[3] << 16);
    H.z = hb[4] | ((unsigned)hb[5] << 16);
    H.w = hb[6] | ((unsigned)hb[7] << 16);
    L.x = lb[0] | ((unsigned)lb[1] << 16);
    L.y = lb[2] | ((unsigned)lb[3] << 16);
    L.z = lb[4] | ((unsigned)lb[5] << 16);
    L.w = lb[6] | ((unsigned)lb[7] << 16);
    u16* dst = (grp == 0) ? qbf : kbf;
    const size_t base = ((size_t)(b * NHEADS + h) * NPIX + p) * 16;
    *(uint4*)&dst[base]     = H;
    *(uint4*)&dst[base + 8] = L;
  } else {
    const int d0 = (grp == 2) ? 0 : 8;
#pragma unroll
    for (int j = 0; j < 8; ++j) {
      vtbf[((size_t)(b * NHEADS + h) * HDV + d0 + j) * NPIX + p] = f2bf(o[j]);
      vf32[((size_t)b * CDIM + h * HDV + d0 + j) * NPIX + p] = o[j];
    }
  }
}

// ---------------- K2: MFMA attention, fine-grained grid ----------------
// 1600 blocks x 256 thr (4 waves): wave (qw = wid&1, kh = wid>>1) handles
// 16 queries (of the block's 32) and key-half kh (800 keys, 25 steps) read
// directly from L2. unroll-5 + launch_bounds(256,6) for ILP + occupancy.
// One barrier for the kh combine; kh=0 waves run the fused pe epilogue.
__global__ __launch_bounds__(256, 6) void k_attn(
    const u16* __restrict__ qbf, const u16* __restrict__ kbf,
    const u16* __restrict__ vtbf, const float* __restrict__ vf32,
    const float* __restrict__ pw, const float* __restrict__ pg,
    const float* __restrict__ pbb, const float* __restrict__ pm,
    const float* __restrict__ pv, float* __restrict__ atb)
{
  const int bh   = blockIdx.x & 31;
  const int qblk = blockIdx.x >> 5;          // 0..49 (32-query chunks)
  const int b = bh >> 3, h = bh & 7;
  const int tid = threadIdx.x;
  const int lane = tid & 63, wid = tid >> 6;
  const int qw = wid & 1, kh = wid >> 1;
  const int qloc = lane & 15, g = lane >> 4;

  __shared__ float red[128][5];   // kh=1 partials: c3[0..3], lsum

  const int qglob = qblk * 32 + qw * 16 + qloc;
  U16B qf;
  qf.u = *(const uint4*)&qbf[((size_t)bh * NPIX + qglob) * 16 + (g & 1) * 8];

  f32x4 c3 = {0.f, 0.f, 0.f, 0.f};
  float lsum = 0.f;
  const int idx0 = (((g & 1) << 5) | qloc) << 2;  // bpermute byte index
  const int idx1 = idx0 + 64;                     // +16 lanes
  const bool selA = (g < 2);
  const f32x4 zf = {0.f, 0.f, 0.f, 0.f};
  const int ksel = (g >> 1) * 8;                  // K-frag hi/lo select

  const u16* kbase = kbf + (size_t)bh * NPIX * 16;
  const u16* vbase = vtbf + ((size_t)bh * HDV + qloc) * NPIX;

#pragma unroll 5
  for (int s = 0; s < 25; ++s) {
    const int key0 = kh * 800 + s * 32;
    // K fragments (A-operand) straight from L2 (hi/lo split-precision QK^T).
    U16B kfA, kfB, vf4;
    kfA.u = *(const uint4*)&kbase[(size_t)(key0 + qloc) * 16 + ksel];
    kfB.u = *(const uint4*)&kbase[(size_t)(key0 + 16 + qloc) * 16 + ksel];
    vf4.u = *(const uint4*)&vbase[key0 + g * 8];   // Vt[d=qloc][keys +8g..]

    f32x4 cA = __builtin_amdgcn_mfma_f32_16x16x32_bf16(kfA.v, qf.v, zf, 0, 0, 0);
    f32x4 cB = __builtin_amdgcn_mfma_f32_16x16x32_bf16(kfB.v, qf.v, zf, 0, 0, 0);

    const float pA0 = __expf(cA[0]), pA1 = __expf(cA[1]);
    const float pA2 = __expf(cA[2]), pA3 = __expf(cA[3]);
    const float pB0 = __expf(cB[0]), pB1 = __expf(cB[1]);
    const float pB2 = __expf(cB[2]), pB3 = __expf(cB[3]);
    // raw-exp lsum: lane covers keys {4g..4g+3} u {16+4g..} of this step for
    // its query; the g-axis is folded by the shfl_xor(16/32) reduce below.
    lsum += ((pA0 + pA1) + (pA2 + pA3)) + ((pB0 + pB1) + (pB2 + pB3));

    const unsigned pkA0 = cvt_pk_bf16(pA0, pA1);
    const unsigned pkA1 = cvt_pk_bf16(pA2, pA3);
    const unsigned pkB0 = cvt_pk_bf16(pB0, pB1);
    const unsigned pkB1 = cvt_pk_bf16(pB2, pB3);

    // Rearrange P (C-layout) -> B-frag layout via 8 bpermute.
    const int a0 = __builtin_amdgcn_ds_bpermute(idx0, (int)pkA0);
    const int b0 = __builtin_amdgcn_ds_bpermute(idx0, (int)pkB0);
    const int a1 = __builtin_amdgcn_ds_bpermute(idx0, (int)pkA1);
    const int b1 = __builtin_amdgcn_ds_bpermute(idx0, (int)pkB1);
    const int a2 = __builtin_amdgcn_ds_bpermute(idx1, (int)pkA0);
    const int b2 = __builtin_amdgcn_ds_bpermute(idx1, (int)pkB0);
    const int a3 = __builtin_amdgcn_ds_bpermute(idx1, (int)pkA1);
    const int b3 = __builtin_amdgcn_ds_bpermute(idx1, (int)pkB1);
    U16B pf;
    pf.u.x = (unsigned)(selA ? a0 : b0);
    pf.u.y = (unsigned)(selA ? a1 : b1);
    pf.u.z = (unsigned)(selA ? a2 : b2);
    pf.u.w = (unsigned)(selA ? a3 : b3);

    c3 = __builtin_amdgcn_mfma_f32_16x16x32_bf16(vf4.v, pf.v, c3, 0, 0, 0);
  }

  // combine key halves across wave pairs (kh=1 -> kh=0); one barrier total
  if (kh == 1) {
    const int rr = qw * 64 + lane;
    red[rr][0] = c3[0]; red[rr][1] = c3[1];
    red[rr][2] = c3[2]; red[rr][3] = c3[3];
    red[rr][4] = lsum;
  }
  __syncthreads();
  if (kh == 1) return;
  {
    const int rr = qw * 64 + lane;
    c3[0] += red[rr][0]; c3[1] += red[rr][1];
    c3[2] += red[rr][2]; c3[3] += red[rr][3];
    lsum  += red[rr][4];
  }

  lsum += __shfl_xor(lsum, 16);
  lsum += __shfl_xor(lsum, 32);
  const float rl = 1.f / lsum;

  // Epilogue: atb[d][p] = c3[r]*rl + BN(dwconv3x3(v))[c=h*16+d][p]
  const int p  = qblk * 32 + qw * 16 + qloc;
  const int yy = p / WIMG, xx = p % WIMG;
  const float* vb = vf32 + ((size_t)b * CDIM + h * HDV) * NPIX;
  float* ob = atb + ((size_t)b * CDIM + h * HDV) * NPIX + p;
#pragma unroll
  for (int r = 0; r < 4; ++r) {
    const int d = g * 4 + r;
    const int c = h * HDV + d;
    float acc = 0.f;
#pragma unroll
    for (int dy = -1; dy <= 1; ++dy)
#pragma unroll
      for (int dx = -1; dx <= 1; ++dx) {
        const int y2 = yy + dy, x2 = xx + dx;
        if ((unsigned)y2 < (unsigned)WIMG && (unsigned)x2 < (unsigned)WIMG)
          acc += pw[c * 9 + (dy + 1) * 3 + (dx + 1)] * vb[(size_t)d * NPIX + y2 * WIMG + x2];
      }
    const float sc = pg[c] * rsqrtf(pv[c] + EPSV);
    const float bi = pbb[c] - pm[c] * sc;
    ob[(size_t)d * NPIX] = c3[r] * rl + acc * sc + bi;
  }
}

// ---------------- K3: y = BN(conv1x1(atb)) -> f32 out ----------------
__global__ __launch_bounds__(256) void k_proj(
    const float* __restrict__ atb, const float* __restrict__ w,
    const float* __restrict__ gg, const float* __restrict__ bb,
    const float* __restrict__ mm, const float* __restrict__ vv,
    float* __restrict__ out)
{
  const int ct   = blockIdx.x % (CDIM / 2);
  const int pblk = (blockIdx.x / (CDIM / 2)) % 7;
  const int b    = blockIdx.x / (7 * (CDIM / 2));
  const int tid  = threadIdx.x;

  __shared__ float wl[2][CDIM];
  wl[tid >> 7][tid & 127] = w[(ct * 2 + (tid >> 7)) * CDIM + (tid & 127)];
  __syncthreads();

  const int p = pblk * 256 + tid;
  if (p >= NPIX) return;

  const float* ab = atb + (size_t)b * CDIM * NPIX + p;
  float a0 = 0.f, a1 = 0.f;
#pragma unroll 16
  for (int ci = 0; ci < CDIM; ++ci) {
    const float xv = ab[(size_t)ci * NPIX];
    a0 += wl[0][ci] * xv;
    a1 += wl[1][ci] * xv;
  }
#pragma unroll
  for (int j = 0; j < 2; ++j) {
    const int c = ct * 2 + j;
    const float sc = gg[c] * rsqrtf(vv[c] + EPSV);
    const float bi = bb[c] - mm[c] * sc;
    out[((size_t)b * CDIM + c) * NPIX + p] = (j ? a1 : a0) * sc + bi;
  }
}

extern "C" void kernel_launch(void* const* d_in, const int* in_sizes, int n_in,
                              void* d_out, int out_size, void* d_ws, size_t ws_size,
                              hipStream_t stream)
{
  const float* x      = (const float*)d_in[0];
  const float* qkv_w  = (const float*)d_in[1];
  const float* qkv_g  = (const float*)d_in[2];
  const float* qkv_b  = (const float*)d_in[3];
  const float* qkv_m  = (const float*)d_in[4];
  const float* qkv_v  = (const float*)d_in[5];
  const float* pe_w   = (const float*)d_in[6];
  const float* pe_g   = (const float*)d_in[7];
  const float* pe_b   = (const float*)d_in[8];
  const float* pe_m   = (const float*)d_in[9];
  const float* pe_v   = (const float*)d_in[10];
  const float* proj_w = (const float*)d_in[11];
  const float* proj_g = (const float*)d_in[12];
  const float* proj_b = (const float*)d_in[13];
  const float* proj_m = (const float*)d_in[14];
  const float* proj_v = (const float*)d_in[15];

  float* ws   = (float*)d_ws;
  float* vf32 = ws;                                  // 819,200 f
  float* atb  = vf32 + (size_t)NB * CDIM * NPIX;     // 819,200 f
  u16*   qbf  = (u16*)(atb + (size_t)NB * CDIM * NPIX);        // 819,200 u16 (hi+lo)
  u16*   kbf  = qbf + (size_t)NB * NHEADS * NPIX * 16;         // 819,200 u16 (hi+lo)
  u16*   vtbf = kbf + (size_t)NB * NHEADS * NPIX * 16;         // 819,200 u16

  k_qkv<<<dim3(NB * (HCH / 8) * 7), 512, 0, stream>>>(
      x, qkv_w, qkv_g, qkv_b, qkv_m, qkv_v, vf32, qbf, kbf, vtbf);
  k_attn<<<dim3(NB * NHEADS * 50), 256, 0, stream>>>(
      qbf, kbf, vtbf, vf32, pe_w, pe_g, pe_b, pe_m, pe_v, atb);
  k_proj<<<dim3(NB * (CDIM / 2) * 7), 256, 0, stream>>>(
      atb, proj_w, proj_g, proj_b, proj_m, proj_v, (float*)d_out);
}